// Round 1
// baseline (469.970 us; speedup 1.0000x reference)
//
#include <hip/hip_runtime.h>

typedef float  f4   __attribute__((ext_vector_type(4)));
typedef __bf16 bf8_t __attribute__((ext_vector_type(8)));
typedef __bf16 bf4_t __attribute__((ext_vector_type(4)));

// ---------------------------------------------------------------------------
// Positional encodings: P[s,2i]=sin(s*10000^(-2i/d)), P[s,2i+1]=cos(...)
// Three tables: d=256 (P1), d=512 (P2), d=1280 (P3), S=128 rows each.
// ---------------------------------------------------------------------------
__global__ __launch_bounds__(256)
void pos_enc_kernel(float* __restrict__ P1, float* __restrict__ P2,
                    float* __restrict__ P3) {
    int idx = blockIdx.x * 256 + threadIdx.x;
    const int n1 = 128 * 256, n2 = 128 * 512, n3 = 128 * 1280;
    float* P; int d, local;
    if (idx < n1)            { P = P1; d = 256;  local = idx; }
    else if (idx < n1 + n2)  { P = P2; d = 512;  local = idx - n1; }
    else if (idx < n1 + n2 + n3) { P = P3; d = 1280; local = idx - n1 - n2; }
    else return;
    int s = local / d;
    int k = local - s * d;
    int i = k >> 1;
    float expo = (-2.0f * (float)i) / (float)d;
    float ang  = (float)s * powf(10000.0f, expo);
    P[local] = (k & 1) ? cosf(ang) : sinf(ang);
}

// ---------------------------------------------------------------------------
// Generic bf16-MFMA GEMM: C = [relu](A[+A2]) @ B + bias) [+ addsrc broadcast]
//   A: fp32 (M x K) row-major, lda; optional A2 added elementwise (same shape)
//   B: fp32 (K x N) row-major, ldb
//   Batched via grid.z = batch*ksplit; per-batch strides sA,sB,sC (elements).
//   If ksplit>1: writes fp32 partials C[(batch*ksplit+kz)*M*N + m*N + n],
//                bias/relu/addsrc skipped (applied by reduce_splitk).
//   Requires: N % 128 == 0, K and kchunk % 32 == 0. M guarded.
//   Block: 256 threads = 4 waves, tile BM=64 x BN=128, BK=32.
//   Wave tile 32x64 => 2x4 MFMA(16x16x32) tiles.
// ---------------------------------------------------------------------------
__global__ __launch_bounds__(256)
void gemm_bf16(const float* __restrict__ A, const float* __restrict__ A2,
               const float* __restrict__ Bm, float* __restrict__ C,
               const float* __restrict__ bias, const float* __restrict__ addsrc,
               int M, int N, int K, int lda, int ldb, int ldc,
               long sA, long sB, long sC, int ksplit, int kchunk, int relu) {
    // pad rows to 56 bf16 = 112 B: 16B-aligned b128 frag reads, ~2-way banks
    __shared__ __align__(16) __bf16 As[64][56];
    __shared__ __align__(16) __bf16 Bs[128][56];

    const int t  = threadIdx.x;
    const int bn = blockIdx.x, bm = blockIdx.y, bz = blockIdx.z;
    const int batch = bz / ksplit;
    const int kz    = bz - batch * ksplit;
    const float* Ab = A + (long)batch * sA;
    const float* Bb = Bm + (long)batch * sB;
    const int m0 = bm * 64, n0 = bn * 128;
    const int kb = kz * kchunk;
    const int ke = (kb + kchunk < K) ? (kb + kchunk) : K;

    const int lane = t & 63;
    const int wv = t >> 6;
    const int wm = wv >> 1, wn = wv & 1;
    const int fr = lane & 15;          // fragment row/col within 16
    const int fq = (lane >> 4) * 8;    // k-offset (elements) of this quarter

    f4 acc[2][4];
#pragma unroll
    for (int mt = 0; mt < 2; ++mt)
#pragma unroll
        for (int nt = 0; nt < 4; ++nt) acc[mt][nt] = (f4){0.f, 0.f, 0.f, 0.f};

    // staging assignment
    const int ar = t >> 2;             // A row 0..63
    const int ak = (t & 3) * 8;        // A k-offset {0,8,16,24}
    const int bc = (t & 31) * 4;       // B col 0..124 step 4
    const int bk = (t >> 5) * 4;       // B k-offset {0,4,...,28}

    const bool avalid = (m0 + ar) < M;
    const int arow = avalid ? (m0 + ar) : 0;
    const float* aptr  = Ab + (long)arow * lda + ak;
    const float* a2ptr = A2 ? (A2 + (long)batch * sA + (long)arow * lda + ak) : nullptr;
    const float* bptr  = Bb + (long)bk * ldb + n0 + bc;

    for (int k0 = kb; k0 < ke; k0 += 32) {
        f4 a0 = (f4){0.f,0.f,0.f,0.f}, a1 = (f4){0.f,0.f,0.f,0.f};
        if (avalid) {
            a0 = *(const f4*)(aptr + k0);
            a1 = *(const f4*)(aptr + k0 + 4);
            if (a2ptr) {
                f4 c0 = *(const f4*)(a2ptr + k0);
                f4 c1 = *(const f4*)(a2ptr + k0 + 4);
                a0 += c0; a1 += c1;
            }
        }
        const float* bp = bptr + (long)k0 * ldb;
        f4 b0 = *(const f4*)bp;
        f4 b1 = *(const f4*)(bp + ldb);
        f4 b2 = *(const f4*)(bp + 2 * ldb);
        f4 b3 = *(const f4*)(bp + 3 * ldb);

        __syncthreads();   // previous iteration's frag reads done
        bf8_t av;
        av[0]=(__bf16)a0[0]; av[1]=(__bf16)a0[1]; av[2]=(__bf16)a0[2]; av[3]=(__bf16)a0[3];
        av[4]=(__bf16)a1[0]; av[5]=(__bf16)a1[1]; av[6]=(__bf16)a1[2]; av[7]=(__bf16)a1[3];
        *(bf8_t*)&As[ar][ak] = av;
#pragma unroll
        for (int i = 0; i < 4; ++i) {
            bf4_t bv = {(__bf16)b0[i], (__bf16)b1[i], (__bf16)b2[i], (__bf16)b3[i]};
            *(bf4_t*)&Bs[bc + i][bk] = bv;   // transposed store: Bs[n][k]
        }
        __syncthreads();

        bf8_t af0 = *(const bf8_t*)&As[wm * 32 + fr][fq];
        bf8_t af1 = *(const bf8_t*)&As[wm * 32 + 16 + fr][fq];
#pragma unroll
        for (int nt = 0; nt < 4; ++nt) {
            bf8_t bfv = *(const bf8_t*)&Bs[wn * 64 + nt * 16 + fr][fq];
            acc[0][nt] = __builtin_amdgcn_mfma_f32_16x16x32_bf16(af0, bfv, acc[0][nt], 0, 0, 0);
            acc[1][nt] = __builtin_amdgcn_mfma_f32_16x16x32_bf16(af1, bfv, acc[1][nt], 0, 0, 0);
        }
    }

    float* Cp; long ldcp;
    const bool fin = (ksplit == 1);
    if (!fin) { Cp = C + (long)(batch * ksplit + kz) * M * N; ldcp = N; }
    else      { Cp = C + (long)batch * sC;                    ldcp = ldc; }

    const int rb = m0 + wm * 32 + (lane >> 4) * 4;  // C row = q*4+v
    const int cb = n0 + wn * 64 + fr;               // C col = lane&15
#pragma unroll
    for (int mt = 0; mt < 2; ++mt) {
#pragma unroll
        for (int nt = 0; nt < 4; ++nt) {
            const int c = cb + nt * 16;
            const float bv = (fin && bias) ? bias[c] : 0.f;
#pragma unroll
            for (int v = 0; v < 4; ++v) {
                const int r = rb + mt * 16 + v;
                if (r < M) {
                    float val = acc[mt][nt][v] + bv;
                    if (fin && relu) val = fmaxf(val, 0.f);
                    if (fin && addsrc) val += addsrc[(long)r * ldcp + c];
                    Cp[(long)r * ldcp + c] = val;
                }
            }
        }
    }
}

// ---------------------------------------------------------------------------
// out[idx] = [relu]( sum_z part[z*MN+idx] + bias[idx%N] ) + addsrc[idx%addmod]
// ---------------------------------------------------------------------------
__global__ __launch_bounds__(256)
void reduce_splitk(const float* __restrict__ part, float* __restrict__ outp,
                   const float* __restrict__ bias, const float* __restrict__ addsrc,
                   int MN, int N, int addmod, int ksplit, int relu) {
    int idx = blockIdx.x * 256 + threadIdx.x;
    if (idx >= MN) return;
    float s = 0.f;
    for (int z = 0; z < ksplit; ++z) s += part[(long)z * MN + idx];
    if (bias) s += bias[idx % N];
    if (relu) s = fmaxf(s, 0.f);
    if (addsrc) s += addsrc[idx % addmod];
    outp[idx] = s;
}

// one wave per row: rs[r] = sum_j h[r*D + j]
__global__ __launch_bounds__(256)
void rowsum_kernel(const float* __restrict__ h, float* __restrict__ rs,
                   int rows, int D) {
    int gw = (blockIdx.x * 256 + threadIdx.x) >> 6;
    int lane = threadIdx.x & 63;
    if (gw >= rows) return;
    const float* p = h + (long)gw * D;
    float s = 0.f;
    for (int j = lane; j < D; j += 64) s += p[j];
    for (int off = 32; off > 0; off >>= 1) s += __shfl_down(s, off, 64);
    if (lane == 0) rs[gw] = s;
}

// out = gA0+gA1+gB0+gB1 + 2*b_p1 + b_p2
__global__ __launch_bounds__(256)
void combine_kernel(const float* __restrict__ gA, const float* __restrict__ gB,
                    const float* __restrict__ bp1, const float* __restrict__ bp2,
                    float* __restrict__ outp, int total, int N) {
    int idx = blockIdx.x * 256 + threadIdx.x;
    if (idx >= total) return;
    int n = idx % N;
    outp[idx] = gA[idx] + gA[total + idx] + gB[idx] + gB[total + idx]
              + 2.f * bp1[n] + bp2[n];
}

// ---------------------------------------------------------------------------
extern "C" void kernel_launch(void* const* d_in, const int* in_sizes, int n_in,
                              void* d_out, int out_size, void* d_ws, size_t ws_size,
                              hipStream_t stream) {
    const float* x       = (const float*)d_in[0];
    const float* W_emb   = (const float*)d_in[1];
    const float* b_emb   = (const float*)d_in[2];
    const float* W_pos1  = (const float*)d_in[3];
    const float* b_pos1  = (const float*)d_in[4];
    const float* W_red   = (const float*)d_in[5];
    const float* b_red   = (const float*)d_in[6];
    const float* W_pos2  = (const float*)d_in[7];
    const float* b_pos2  = (const float*)d_in[8];
    const float* W_red2  = (const float*)d_in[9];
    const float* b_red2  = (const float*)d_in[10];
    const float* W_pos3  = (const float*)d_in[11];
    const float* b_pos3  = (const float*)d_in[12];
    const float* W_down2 = (const float*)d_in[13];
    const float* b_down2 = (const float*)d_in[14];
    const float* W_flat  = (const float*)d_in[15];
    const float* b_flat  = (const float*)d_in[16];
    const float* W_d1    = (const float*)d_in[17];
    const float* b_d1    = (const float*)d_in[18];
    const float* W_d2    = (const float*)d_in[19];
    const float* b_d2    = (const float*)d_in[20];
    const float* W_d3    = (const float*)d_in[21];
    const float* b_d3    = (const float*)d_in[22];
    const float* W_p1    = (const float*)d_in[23];
    const float* b_p1    = (const float*)d_in[24];
    const float* W_p2    = (const float*)d_in[25];
    const float* b_p2    = (const float*)d_in[26];
    float* out = (float*)d_out;
    float* ws  = (float*)d_ws;

    // ---- workspace layout (floats) ----
    size_t o = 0;
    auto alloc = [&](size_t n) { size_t p = o; o += (n + 63) & ~(size_t)63; return p; };
    const size_t oP1 = alloc(128 * 256);
    const size_t oP2 = alloc(128 * 512);
    const size_t oP3 = alloc(128 * 1280);
    const size_t oQ1 = alloc(128 * 128);     // relu(P1@W_pos1+b)
    const size_t oQ2 = alloc(128 * 256);
    const size_t oQ3 = alloc(128 * 640);
    const size_t oH1 = alloc(2048 * 128);
    const size_t oRS1 = alloc(2048);
    const size_t oRS2 = alloc(2048);
    const size_t oH2 = alloc(2048 * 256);
    const size_t oH3 = alloc(2048 * 640);
    const size_t oH4 = alloc(2048 * 512);
    const size_t oH5 = alloc(16 * 512);
    const size_t oH6 = alloc(16 * 512);
    const size_t oH7 = alloc(16 * 512);
    const size_t oH8 = alloc(16 * 512);
    // regionB: M1 (2 MB) + M2 (10.5 MB); reused later for gA/gB (4 MB each)
    const size_t oRegB = alloc(524288 + 2621440);
    const size_t oM1 = oRegB, oM2 = oRegB + 524288;
    const size_t oGA = oRegB, oGB = oRegB + 1024000;
    // regionA: partG1 (20x2048x128 = 20 MB); reused for partD (8 MB) + partF (4 MB)
    const size_t oRegA = alloc(20u * 2048 * 128);
    const size_t oPartG1 = oRegA, oPartD = oRegA, oPartF = oRegA + 2097152;
    (void)ws_size; (void)in_sizes; (void)n_in; (void)out_size;

    dim3 blk(256);
    auto gemm = [&](const float* A, const float* A2v, const float* B, float* C,
                    const float* bias, const float* addsrc,
                    int M, int N, int K, int lda, int ldb, int ldc,
                    long sA, long sB, long sC, int batch, int ksplit, int kchunk,
                    int relu) {
        dim3 grid(N / 128, (M + 63) / 64, batch * ksplit);
        gemm_bf16<<<grid, blk, 0, stream>>>(A, A2v, B, C, bias, addsrc,
                                            M, N, K, lda, ldb, ldc,
                                            sA, sB, sC, ksplit, kchunk, relu);
    };

    // 1. positional encoding tables
    pos_enc_kernel<<<dim3(1024), blk, 0, stream>>>(ws + oP1, ws + oP2, ws + oP3);
    // 2-4. pos projections: Q = relu(P @ W_pos + b_pos)
    gemm(ws + oP1, nullptr, W_pos1, ws + oQ1, b_pos1, nullptr,
         128, 128, 256, 256, 128, 128, 0, 0, 0, 1, 1, 256, 1);
    gemm(ws + oP2, nullptr, W_pos2, ws + oQ2, b_pos2, nullptr,
         128, 256, 512, 512, 256, 256, 0, 0, 0, 1, 1, 512, 1);
    gemm(ws + oP3, nullptr, W_pos3, ws + oQ3, b_pos3, nullptr,
         128, 640, 1280, 1280, 640, 640, 0, 0, 0, 1, 1, 1280, 1);
    // 5. GEMM1: x(2048x32000) @ W_emb(32000x128), split-K 20
    gemm(x, nullptr, W_emb, ws + oPartG1, nullptr, nullptr,
         2048, 128, 32000, 32000, 128, 128, 0, 0, 0, 1, 20, 1600, 0);
    // 6. h1 = relu(sum + b_emb) + Q1[s,n]
    reduce_splitk<<<dim3(1024), blk, 0, stream>>>(ws + oPartG1, ws + oH1, b_emb,
                                                  ws + oQ1, 262144, 128, 16384, 20, 1);
    // 7. rs1
    rowsum_kernel<<<dim3(512), blk, 0, stream>>>(ws + oH1, ws + oRS1, 2048, 128);
    // 8. M1 = rs1(16x128) @ W_red viewed (128 x 32768)
    gemm(ws + oRS1, nullptr, W_red, ws + oM1, nullptr, nullptr,
         16, 32768, 128, 128, 32768, 32768, 0, 0, 0, 1, 1, 128, 0);
    // 9. h2 = relu(h1[b] @ M1[b] + b_red) + Q2  (batched)
    gemm(ws + oH1, nullptr, ws + oM1, ws + oH2, b_red, ws + oQ2,
         128, 256, 128, 128, 256, 256, 16384, 32768, 32768, 16, 1, 128, 1);
    // 10. rs2
    rowsum_kernel<<<dim3(512), blk, 0, stream>>>(ws + oH2, ws + oRS2, 2048, 256);
    // 11. M2 = rs2(16x128) @ W_red2 viewed (128 x 163840)
    gemm(ws + oRS2, nullptr, W_red2, ws + oM2, nullptr, nullptr,
         16, 163840, 128, 128, 163840, 163840, 0, 0, 0, 1, 1, 128, 0);
    // 12. h3 = relu(h2[b] @ M2[b] + b_red2) + Q3  (batched)
    gemm(ws + oH2, nullptr, ws + oM2, ws + oH3, b_red2, ws + oQ3,
         128, 640, 256, 256, 640, 640, 32768, 163840, 81920, 16, 1, 256, 1);
    // 13-14. h4 = relu(h3(2048x640) @ W_down2 + b_down2), split-K 2
    gemm(ws + oH3, nullptr, W_down2, ws + oPartD, nullptr, nullptr,
         2048, 512, 640, 640, 512, 512, 0, 0, 0, 1, 2, 320, 0);
    reduce_splitk<<<dim3(4096), blk, 0, stream>>>(ws + oPartD, ws + oH4, b_down2,
                                                  nullptr, 1048576, 512, 1, 2, 1);
    // 15-16. h5 = relu(h4 viewed (16x65536) @ W_flat + b_flat), split-K 128
    gemm(ws + oH4, nullptr, W_flat, ws + oPartF, nullptr, nullptr,
         16, 512, 65536, 65536, 512, 512, 0, 0, 0, 1, 128, 512, 0);
    reduce_splitk<<<dim3(32), blk, 0, stream>>>(ws + oPartF, ws + oH5, b_flat,
                                                nullptr, 8192, 512, 1, 128, 1);
    // 17-19. dense chain
    gemm(ws + oH5, nullptr, W_d1, ws + oH6, b_d1, nullptr,
         16, 512, 512, 512, 512, 512, 0, 0, 0, 1, 1, 512, 1);
    gemm(ws + oH6, nullptr, W_d2, ws + oH7, b_d2, nullptr,
         16, 512, 512, 512, 512, 512, 0, 0, 0, 1, 1, 512, 1);
    gemm(ws + oH7, nullptr, W_d3, ws + oH8, b_d3, nullptr,
         16, 512, 512, 512, 512, 512, 0, 0, 0, 1, 1, 512, 1);
    // 20. gA = (h6+h8) @ W_p1   (split-K 2, partials)
    gemm(ws + oH6, ws + oH8, W_p1, ws + oGA, nullptr, nullptr,
         16, 32000, 512, 512, 32000, 32000, 0, 0, 0, 1, 2, 256, 0);
    // 21. gB = h7 @ W_p2        (split-K 2, partials)
    gemm(ws + oH7, nullptr, W_p2, ws + oGB, nullptr, nullptr,
         16, 32000, 512, 512, 32000, 32000, 0, 0, 0, 1, 2, 256, 0);
    // 22. out = gA + gB + 2*b_p1 + b_p2
    combine_kernel<<<dim3(2000), blk, 0, stream>>>(ws + oGA, ws + oGB, b_p1, b_p2,
                                                   out, 512000, 32000);
}

// Round 2
// 459.787 us; speedup vs baseline: 1.0221x; 1.0221x over previous
//
#include <hip/hip_runtime.h>

typedef float  f4   __attribute__((ext_vector_type(4)));
typedef __bf16 bf8_t __attribute__((ext_vector_type(8)));
typedef __bf16 bf4_t __attribute__((ext_vector_type(4)));

// ---------------------------------------------------------------------------
// Positional encodings: P[s,2i]=sin(s*10000^(-2i/d)), P[s,2i+1]=cos(...)
// ---------------------------------------------------------------------------
__global__ __launch_bounds__(256)
void pos_enc_kernel(float* __restrict__ P1, float* __restrict__ P2,
                    float* __restrict__ P3) {
    int idx = blockIdx.x * 256 + threadIdx.x;
    const int n1 = 128 * 256, n2 = 128 * 512, n3 = 128 * 1280;
    float* P; int d, local;
    if (idx < n1)            { P = P1; d = 256;  local = idx; }
    else if (idx < n1 + n2)  { P = P2; d = 512;  local = idx - n1; }
    else if (idx < n1 + n2 + n3) { P = P3; d = 1280; local = idx - n1 - n2; }
    else return;
    int s = local / d;
    int k = local - s * d;
    int i = k >> 1;
    float expo = (-2.0f * (float)i) / (float)d;
    float ang  = (float)s * powf(10000.0f, expo);
    P[local] = (k & 1) ? cosf(ang) : sinf(ang);
}

// bias_comb[n] = 2*b_p1[n] + b_p2[n]
__global__ __launch_bounds__(256)
void biascomb_kernel(const float* __restrict__ bp1, const float* __restrict__ bp2,
                     float* __restrict__ bc, int n) {
    int idx = blockIdx.x * 256 + threadIdx.x;
    if (idx < n) bc[idx] = 2.f * bp1[idx] + bp2[idx];
}

// ---------------------------------------------------------------------------
// Generic bf16-MFMA GEMM with register double-buffer prefetch.
//   C = [relu]((A[+A2]) @ B + bias) [+ addsrc]   (fp32 in/out, bf16 MFMA)
//   ksplit>1: writes fp32 partials, epilogue ops deferred to reduce kernel.
//   xcdmap=1: grid is 1-D (1024); decode so all blocks of one k-slice land on
//   one XCD (assumes round-robin blockIdx%8 placement). Requires M-blocks=32,
//   ksplit=32, N=128.
//   Block 256 thr = 4 waves; tile BM=64 x BN=128, BK=32; wave tile 32x64.
// ---------------------------------------------------------------------------
__global__ __launch_bounds__(256)
void gemm_bf16(const float* __restrict__ A, const float* __restrict__ A2,
               const float* __restrict__ Bm, float* __restrict__ C,
               const float* __restrict__ bias, const float* __restrict__ addsrc,
               int M, int N, int K, int lda, int ldb, int ldc,
               long sA, long sB, long sC, int ksplit, int kchunk, int relu,
               int xcdmap) {
    __shared__ __align__(16) __bf16 As[64][56];
    __shared__ __align__(16) __bf16 Bs[128][56];

    const int t = threadIdx.x;
    int bn, bm, bz;
    if (xcdmap) {
        const int lin = blockIdx.x;
        const int xc = lin & 7, j = lin >> 3;
        bz = xc + ((j >> 5) << 3);   // kz: 4 slices per XCD
        bm = j & 31;
        bn = 0;
    } else {
        bn = blockIdx.x; bm = blockIdx.y; bz = blockIdx.z;
    }
    const int batch = bz / ksplit;
    const int kz    = bz - batch * ksplit;
    const float* Ab = A + (long)batch * sA;
    const float* Bb = Bm + (long)batch * sB;
    const int m0 = bm * 64, n0 = bn * 128;
    const int kb = kz * kchunk;
    const int ke = (kb + kchunk < K) ? (kb + kchunk) : K;

    const int lane = t & 63;
    const int wv = t >> 6;
    const int wm = wv >> 1, wn = wv & 1;
    const int fr = lane & 15;
    const int fq = (lane >> 4) * 8;

    f4 acc[2][4];
#pragma unroll
    for (int mt = 0; mt < 2; ++mt)
#pragma unroll
        for (int nt = 0; nt < 4; ++nt) acc[mt][nt] = (f4){0.f, 0.f, 0.f, 0.f};

    const int ar = t >> 2;
    const int ak = (t & 3) * 8;
    const int bc = (t & 31) * 4;
    const int bk = (t >> 5) * 4;

    const bool avalid = (m0 + ar) < M;
    const int arow = avalid ? (m0 + ar) : 0;
    const float* aptr  = Ab + (long)arow * lda + ak;
    const float* a2ptr = A2 ? (A2 + (long)batch * sA + (long)arow * lda + ak) : nullptr;
    const float* bptr  = Bb + (long)bk * ldb + n0 + bc;

    auto loadA = [&](int k0, f4& r0, f4& r1) {
        r0 = (f4){0.f,0.f,0.f,0.f}; r1 = (f4){0.f,0.f,0.f,0.f};
        if (avalid) {
            r0 = *(const f4*)(aptr + k0);
            r1 = *(const f4*)(aptr + k0 + 4);
            if (a2ptr) {
                r0 += *(const f4*)(a2ptr + k0);
                r1 += *(const f4*)(a2ptr + k0 + 4);
            }
        }
    };
    auto loadB = [&](int k0, f4& r0, f4& r1, f4& r2, f4& r3) {
        const float* bp = bptr + (long)k0 * ldb;
        r0 = *(const f4*)bp;
        r1 = *(const f4*)(bp + ldb);
        r2 = *(const f4*)(bp + 2 * ldb);
        r3 = *(const f4*)(bp + 3 * ldb);
    };

    f4 ca0, ca1, cb0, cb1, cb2, cb3;
    loadA(kb, ca0, ca1);
    loadB(kb, cb0, cb1, cb2, cb3);

    for (int k0 = kb; k0 < ke; k0 += 32) {
        f4 na0, na1, nb0, nb1, nb2, nb3;
        const int kn = k0 + 32;
        const bool hn = kn < ke;
        if (hn) {                       // prefetch next tile into registers
            loadA(kn, na0, na1);
            loadB(kn, nb0, nb1, nb2, nb3);
        }
        __syncthreads();                // prior frag reads done
        bf8_t av;
        av[0]=(__bf16)ca0[0]; av[1]=(__bf16)ca0[1]; av[2]=(__bf16)ca0[2]; av[3]=(__bf16)ca0[3];
        av[4]=(__bf16)ca1[0]; av[5]=(__bf16)ca1[1]; av[6]=(__bf16)ca1[2]; av[7]=(__bf16)ca1[3];
        *(bf8_t*)&As[ar][ak] = av;
#pragma unroll
        for (int i = 0; i < 4; ++i) {
            bf4_t bv = {(__bf16)cb0[i], (__bf16)cb1[i], (__bf16)cb2[i], (__bf16)cb3[i]};
            *(bf4_t*)&Bs[bc + i][bk] = bv;
        }
        __syncthreads();

        bf8_t af0 = *(const bf8_t*)&As[wm * 32 + fr][fq];
        bf8_t af1 = *(const bf8_t*)&As[wm * 32 + 16 + fr][fq];
#pragma unroll
        for (int nt = 0; nt < 4; ++nt) {
            bf8_t bfv = *(const bf8_t*)&Bs[wn * 64 + nt * 16 + fr][fq];
            acc[0][nt] = __builtin_amdgcn_mfma_f32_16x16x32_bf16(af0, bfv, acc[0][nt], 0, 0, 0);
            acc[1][nt] = __builtin_amdgcn_mfma_f32_16x16x32_bf16(af1, bfv, acc[1][nt], 0, 0, 0);
        }
        if (hn) { ca0=na0; ca1=na1; cb0=nb0; cb1=nb1; cb2=nb2; cb3=nb3; }
    }

    float* Cp; long ldcp;
    const bool fin = (ksplit == 1);
    if (!fin) { Cp = C + (long)(batch * ksplit + kz) * M * N; ldcp = N; }
    else      { Cp = C + (long)batch * sC;                    ldcp = ldc; }

    const int rb = m0 + wm * 32 + (lane >> 4) * 4;
    const int cb2_ = n0 + wn * 64 + fr;
#pragma unroll
    for (int mt = 0; mt < 2; ++mt) {
#pragma unroll
        for (int nt = 0; nt < 4; ++nt) {
            const int c = cb2_ + nt * 16;
            const float bv = (fin && bias) ? bias[c] : 0.f;
#pragma unroll
            for (int v = 0; v < 4; ++v) {
                const int r = rb + mt * 16 + v;
                if (r < M) {
                    float val = acc[mt][nt][v] + bv;
                    if (fin && relu) val = fmaxf(val, 0.f);
                    if (fin && addsrc) val += addsrc[(long)r * ldcp + c];
                    Cp[(long)r * ldcp + c] = val;
                }
            }
        }
    }
}

// out[idx] = [relu](sum_z part[z*MN+idx] + bias[idx%N]) + addsrc[idx%addmod]
__global__ __launch_bounds__(256)
void reduce_splitk(const float* __restrict__ part, float* __restrict__ outp,
                   const float* __restrict__ bias, const float* __restrict__ addsrc,
                   int MN, int N, int addmod, int ksplit, int relu) {
    int idx = blockIdx.x * 256 + threadIdx.x;
    if (idx >= MN) return;
    float s = 0.f;
    for (int z = 0; z < ksplit; ++z) s += part[(long)z * MN + idx];
    if (bias) s += bias[idx % N];
    if (relu) s = fmaxf(s, 0.f);
    if (addsrc) s += addsrc[idx % addmod];
    outp[idx] = s;
}

// Fused GEMM1 reduce: h1 = relu(sum_z part + b_emb) + Q1, and rs1 = rowsum(h1).
// grid 1024 x 256: block covers 2 rows of 128 cols. ksplit=32.
__global__ __launch_bounds__(256)
void reduce_rs_kernel(const float* __restrict__ part, float* __restrict__ h1,
                      const float* __restrict__ bias, const float* __restrict__ Q1,
                      float* __restrict__ rs1, int ksplit) {
    const int t = threadIdx.x;
    const int idx = blockIdx.x * 256 + t;
    float s = 0.f;
    for (int z = 0; z < ksplit; ++z) s += part[(long)z * 262144 + idx];
    s += bias[idx & 127];
    s = fmaxf(s, 0.f);
    s += Q1[idx & 16383];
    h1[idx] = s;
    float r = s;
    for (int off = 32; off > 0; off >>= 1) r += __shfl_down(r, off, 64);
    __shared__ float p[4];
    const int w = t >> 6, lane = t & 63;
    if (lane == 0) p[w] = r;
    __syncthreads();
    if (t < 2) rs1[(blockIdx.x << 1) + t] = p[t * 2] + p[t * 2 + 1];
}

// one wave per row: rs[r] = sum_j h[r*D + j]
__global__ __launch_bounds__(256)
void rowsum_kernel(const float* __restrict__ h, float* __restrict__ rs,
                   int rows, int D) {
    int gw = (blockIdx.x * 256 + threadIdx.x) >> 6;
    int lane = threadIdx.x & 63;
    if (gw >= rows) return;
    const float* p = h + (long)gw * D;
    float s = 0.f;
    for (int j = lane; j < D; j += 64) s += p[j];
    for (int off = 32; off > 0; off >>= 1) s += __shfl_down(s, off, 64);
    if (lane == 0) rs[gw] = s;
}

// ---------------------------------------------------------------------------
extern "C" void kernel_launch(void* const* d_in, const int* in_sizes, int n_in,
                              void* d_out, int out_size, void* d_ws, size_t ws_size,
                              hipStream_t stream) {
    const float* x       = (const float*)d_in[0];
    const float* W_emb   = (const float*)d_in[1];
    const float* b_emb   = (const float*)d_in[2];
    const float* W_pos1  = (const float*)d_in[3];
    const float* b_pos1  = (const float*)d_in[4];
    const float* W_red   = (const float*)d_in[5];
    const float* b_red   = (const float*)d_in[6];
    const float* W_pos2  = (const float*)d_in[7];
    const float* b_pos2  = (const float*)d_in[8];
    const float* W_red2  = (const float*)d_in[9];
    const float* b_red2  = (const float*)d_in[10];
    const float* W_pos3  = (const float*)d_in[11];
    const float* b_pos3  = (const float*)d_in[12];
    const float* W_down2 = (const float*)d_in[13];
    const float* b_down2 = (const float*)d_in[14];
    const float* W_flat  = (const float*)d_in[15];
    const float* b_flat  = (const float*)d_in[16];
    const float* W_d1    = (const float*)d_in[17];
    const float* b_d1    = (const float*)d_in[18];
    const float* W_d2    = (const float*)d_in[19];
    const float* b_d2    = (const float*)d_in[20];
    const float* W_d3    = (const float*)d_in[21];
    const float* b_d3    = (const float*)d_in[22];
    const float* W_p1    = (const float*)d_in[23];
    const float* b_p1    = (const float*)d_in[24];
    const float* W_p2    = (const float*)d_in[25];
    const float* b_p2    = (const float*)d_in[26];
    float* out = (float*)d_out;
    float* ws  = (float*)d_ws;

    size_t o = 0;
    auto alloc = [&](size_t n) { size_t p = o; o += (n + 63) & ~(size_t)63; return p; };
    const size_t oP1 = alloc(128 * 256);
    const size_t oP2 = alloc(128 * 512);
    const size_t oP3 = alloc(128 * 1280);
    const size_t oQ1 = alloc(128 * 128);
    const size_t oQ2 = alloc(128 * 256);
    const size_t oQ3 = alloc(128 * 640);
    const size_t oBC = alloc(32000);
    const size_t oH1 = alloc(2048 * 128);
    const size_t oRS1 = alloc(2048);
    const size_t oRS2 = alloc(2048);
    const size_t oH2 = alloc(2048 * 256);
    const size_t oH3 = alloc(2048 * 640);
    const size_t oH4 = alloc(2048 * 512);
    const size_t oH5 = alloc(16 * 512);
    const size_t oH6 = alloc(16 * 512);
    const size_t oH7 = alloc(16 * 512);
    const size_t oH8 = alloc(16 * 512);
    const size_t oM1 = alloc(16 * 32768);
    const size_t oM2 = alloc(16 * 163840);
    // RegA reused: Q3 partials (4x81920) -> GEMM1 partials (32x262144) -> W_flat partials (128x8192)
    const size_t oRegA = alloc(32u * 262144);
    const size_t oPartQ3 = oRegA, oPartG1 = oRegA, oPartF = oRegA;
    (void)ws_size; (void)in_sizes; (void)n_in; (void)out_size;

    dim3 blk(256);
    auto gemm = [&](const float* A, const float* A2v, const float* B, float* C,
                    const float* bias, const float* addsrc,
                    int M, int N, int K, int lda, int ldb, int ldc,
                    long sA, long sB, long sC, int batch, int ksplit, int kchunk,
                    int relu) {
        dim3 grid(N / 128, (M + 63) / 64, batch * ksplit);
        gemm_bf16<<<grid, blk, 0, stream>>>(A, A2v, B, C, bias, addsrc,
                                            M, N, K, lda, ldb, ldc,
                                            sA, sB, sC, ksplit, kchunk, relu, 0);
    };

    // 1. positional encodings + combined projection bias
    pos_enc_kernel<<<dim3(1024), blk, 0, stream>>>(ws + oP1, ws + oP2, ws + oP3);
    biascomb_kernel<<<dim3(125), blk, 0, stream>>>(b_p1, b_p2, ws + oBC, 32000);
    // 2-4. pos projections Q = relu(P @ W_pos + b)
    gemm(ws + oP1, nullptr, W_pos1, ws + oQ1, b_pos1, nullptr,
         128, 128, 256, 256, 128, 128, 0, 0, 0, 1, 1, 256, 1);
    gemm(ws + oP2, nullptr, W_pos2, ws + oQ2, b_pos2, nullptr,
         128, 256, 512, 512, 256, 256, 0, 0, 0, 1, 1, 512, 1);
    gemm(ws + oP3, nullptr, W_pos3, ws + oPartQ3, nullptr, nullptr,
         128, 640, 1280, 1280, 640, 640, 0, 0, 0, 1, 4, 320, 0);
    reduce_splitk<<<dim3(320), blk, 0, stream>>>(ws + oPartQ3, ws + oQ3, b_pos3,
                                                 nullptr, 81920, 640, 1, 4, 1);
    // 5. GEMM1: x(2048x32000) @ W_emb, split-K 32, XCD-grouped
    gemm_bf16<<<dim3(1024), blk, 0, stream>>>(x, nullptr, W_emb, ws + oPartG1,
                                              nullptr, nullptr,
                                              2048, 128, 32000, 32000, 128, 128,
                                              0, 0, 0, 32, 1024, 0, 1);
    // 6. h1 = relu(sum + b_emb) + Q1 ; rs1 = rowsum(h1)
    reduce_rs_kernel<<<dim3(1024), blk, 0, stream>>>(ws + oPartG1, ws + oH1, b_emb,
                                                     ws + oQ1, ws + oRS1, 32);
    // 7. M1 = rs1(16x128) @ W_red viewed (128 x 32768)
    gemm(ws + oRS1, nullptr, W_red, ws + oM1, nullptr, nullptr,
         16, 32768, 128, 128, 32768, 32768, 0, 0, 0, 1, 1, 128, 0);
    // 8. h2 = relu(h1[b] @ M1[b] + b_red) + Q2  (batched)
    gemm(ws + oH1, nullptr, ws + oM1, ws + oH2, b_red, ws + oQ2,
         128, 256, 128, 128, 256, 256, 16384, 32768, 32768, 16, 1, 128, 1);
    // 9. rs2
    rowsum_kernel<<<dim3(512), blk, 0, stream>>>(ws + oH2, ws + oRS2, 2048, 256);
    // 10. M2 = rs2(16x128) @ W_red2 viewed (128 x 163840)
    gemm(ws + oRS2, nullptr, W_red2, ws + oM2, nullptr, nullptr,
         16, 163840, 128, 128, 163840, 163840, 0, 0, 0, 1, 1, 128, 0);
    // 11. h3 = relu(h2[b] @ M2[b] + b_red2) + Q3  (batched)
    gemm(ws + oH2, nullptr, ws + oM2, ws + oH3, b_red2, ws + oQ3,
         128, 640, 256, 256, 640, 640, 32768, 163840, 81920, 16, 1, 256, 1);
    // 12. h4 = relu(h3 @ W_down2 + b_down2), single-pass
    gemm(ws + oH3, nullptr, W_down2, ws + oH4, b_down2, nullptr,
         2048, 512, 640, 640, 512, 512, 0, 0, 0, 1, 1, 640, 1);
    // 13-14. h5 = relu(h4 viewed (16x65536) @ W_flat + b_flat), split-K 128
    gemm(ws + oH4, nullptr, W_flat, ws + oPartF, nullptr, nullptr,
         16, 512, 65536, 65536, 512, 512, 0, 0, 0, 1, 128, 512, 0);
    reduce_splitk<<<dim3(32), blk, 0, stream>>>(ws + oPartF, ws + oH5, b_flat,
                                                nullptr, 8192, 512, 1, 128, 1);
    // 15-17. dense chain
    gemm(ws + oH5, nullptr, W_d1, ws + oH6, b_d1, nullptr,
         16, 512, 512, 512, 512, 512, 0, 0, 0, 1, 1, 512, 1);
    gemm(ws + oH6, nullptr, W_d2, ws + oH7, b_d2, nullptr,
         16, 512, 512, 512, 512, 512, 0, 0, 0, 1, 1, 512, 1);
    gemm(ws + oH7, nullptr, W_d3, ws + oH8, b_d3, nullptr,
         16, 512, 512, 512, 512, 512, 0, 0, 0, 1, 1, 512, 1);
    // 18. out  = (h6+h8) @ W_p1 + (2*b_p1 + b_p2)
    gemm(ws + oH6, ws + oH8, W_p1, out, ws + oBC, nullptr,
         16, 32000, 512, 512, 32000, 32000, 0, 0, 0, 1, 1, 512, 0);
    // 19. out += h7 @ W_p2
    gemm(ws + oH7, nullptr, W_p2, out, nullptr, out,
         16, 32000, 512, 512, 32000, 32000, 0, 0, 0, 1, 1, 512, 0);
}